// Round 2
// baseline (1336.976 us; speedup 1.0000x reference)
//
#include <hip/hip_runtime.h>
#include <hip/hip_bf16.h>

#define LK 0.01f
__device__ __forceinline__ float lrelu(float x){ return x >= 0.f ? x : LK * x; }

// Problem dims
#define NB 2
#define CMS 8       // band_ms
#define CHS 128     // band_hs
#define HW 512
#define HSIN 128    // hsi spatial
#define OS 32       // q/k spatial
#define K72 72      // 8 ch * 9 taps

// Workspace layout (float offsets). Total ~4.64M floats = 18.6 MB.
#define OFF_V   0                        // v fp32 [2][8][512][512]
#define SZ_V    (NB*CMS*HW*HW)
#define OFF_Q   (OFF_V + SZ_V)           // q fp32 [2][8][32][32]
#define SZ_Q    (NB*CMS*OS*OS)
#define OFF_K   (OFF_Q + SZ_Q)           // k fp32 [2][128][32][32]
#define SZ_K    (NB*CHS*OS*OS)
#define OFF_BN  (OFF_K + SZ_K)           // band norms [16] (pad 64)
#define OFF_AR  (OFF_BN + 64)            // att raw [2][8][128]
#define SZ_AR   (NB*CMS*CHS)
#define OFF_A2  (OFF_AR + SZ_AR)         // att softmaxed/6 [2][8][128]
#define OFF_WE  (OFF_A2 + SZ_AR)         // WeffT fp32 [n][72][128]
#define SZ_WE   (NB*K72*CHS)
#define OFF_WKT (OFF_WE + SZ_WE)         // Wk transposed fp32 [1152][128]
#define SZ_WKT  (1152*CHS)
#define OFF_WVT (OFF_WKT + SZ_WKT)       // Wv transposed fp32 [72][8]
#define SZ_WVT  (K72*CMS)

// ---------------- prep: transpose Wk and Wv to k-major ----------------
__global__ void prep_kernel(const float* __restrict__ Wk, const float* __restrict__ Wv,
                            float* __restrict__ wkt, float* __restrict__ wvT){
  int idx = blockIdx.x * 256 + threadIdx.x;
  if (idx < 147456){
    int co = idx & 127, kk = idx >> 7;
    wkt[kk*128 + co] = Wk[co*1152 + kk];
  } else if (idx < 147456 + 576){
    int l = idx - 147456;
    int co = l & 7, kt = l >> 3;
    wvT[kt*8 + co] = Wv[co*72 + kt];
  }
}

// ---------------- conv_v: 3x3 s1 p1, 8->8, lrelu, fp32 out ----------------
// Block = (xt,yt,n), 32x32 pixel tile, 256 threads. Weights via wave-uniform
// scalar loads (SGPR), input tile in LDS.
__global__ __launch_bounds__(256, 4)
void conv_v_kernel(const float* __restrict__ hrms, const float* __restrict__ wvT,
                   const float* __restrict__ bv, float* __restrict__ v){
  __shared__ float vt[CMS][34][36];
  int xt = blockIdx.x, yt = blockIdx.y, n = blockIdx.z;
  int tid = threadIdx.x;
  for (int l = tid; l < CMS*34*34; l += 256){
    int ci = l / 1156, r = l % 1156, yy = r / 34, xx = r % 34;
    int gy = yt*32 + yy - 1, gx = xt*32 + xx - 1;
    float val = 0.f;
    if ((unsigned)gy < HW && (unsigned)gx < HW)
      val = hrms[((n*CMS+ci)*HW + gy)*HW + gx];
    vt[ci][yy][xx] = val;
  }
  __syncthreads();
  int wid = __builtin_amdgcn_readfirstlane(tid >> 6);  // wave id, uniform
  int lane = tid & 63;
  int lrow = lane >> 5, lx = lane & 31;
  for (int s = wid; s < 16; s += 4){                   // 16 strips of 2 rows
    int r0 = s*2 + lrow;
    float acc[8];
    #pragma unroll
    for (int c = 0; c < 8; c++) acc[c] = 0.f;
    #pragma unroll
    for (int ci = 0; ci < 8; ci++){
      #pragma unroll
      for (int tap = 0; tap < 9; tap++){
        float vv = vt[ci][r0 + tap/3][lx + tap%3];
        const float* wrow = wvT + (ci*9 + tap)*8;      // uniform -> s_load
        #pragma unroll
        for (int c = 0; c < 8; c++) acc[c] += wrow[c] * vv;
      }
    }
    int gy = yt*32 + r0, gx = xt*32 + lx;
    #pragma unroll
    for (int c = 0; c < 8; c++)
      v[((n*CMS+c)*HW + gy)*HW + gx] = lrelu(acc[c] + bv[c]);
  }
}

// ---------------- conv_q: 3x3 stride 16 p1, 8->8, lrelu ----------------
__global__ void conv_q_kernel(const float* __restrict__ msi, const float* __restrict__ Wq,
                              const float* __restrict__ bq, float* __restrict__ q){
  int idx = blockIdx.x * 256 + threadIdx.x;   // 16384 outputs
  int x = idx & 31, y = (idx >> 5) & 31, co = (idx >> 10) & 7, n = idx >> 13;
  float acc = bq[co];
  for (int ci = 0; ci < 8; ci++){
    #pragma unroll
    for (int tap = 0; tap < 9; tap++){
      int yi = y*16 + tap/3 - 1, xi = x*16 + tap%3 - 1;
      if ((unsigned)yi < HW && (unsigned)xi < HW)
        acc += msi[((n*CMS+ci)*HW + yi)*HW + xi] * Wq[co*72 + ci*9 + tap];
    }
  }
  q[idx] = lrelu(acc);
}

// ---------------- per-band L2 norms of q ----------------
__global__ void bandnorm_kernel(const float* __restrict__ q, float* __restrict__ bn){
  int b = blockIdx.x;                 // n*8+i, 16 blocks
  int tid = threadIdx.x;              // 256
  const float* qb = q + b*1024;
  float s = 0.f;
  for (int j = tid; j < 1024; j += 256){ float v = qb[j]; s += v*v; }
  __shared__ float red[4];
  for (int off = 32; off; off >>= 1) s += __shfl_down(s, off);
  if ((tid & 63) == 0) red[tid >> 6] = s;
  __syncthreads();
  if (tid == 0) bn[b] = sqrtf(red[0] + red[1] + red[2] + red[3]);
}

// ---------------- conv_k: 3x3 stride 4 p1, 128->128, lrelu ----------------
// Block = (xg,y,n): 4 output x positions, 128 threads = c_out.
__global__ void conv_k_kernel(const float* __restrict__ hsi, const float* __restrict__ wkt,
                              const float* __restrict__ bk, float* __restrict__ kw){
  __shared__ __align__(16) float patch[1152][4];
  int xg = blockIdx.x, y = blockIdx.y, n = blockIdx.z;
  int tid = threadIdx.x;
  for (int l = tid; l < 4608; l += 128){
    int kk = l >> 2, xi = l & 3;
    int ci = kk / 9, tap = kk % 9;
    int gy = 4*y + tap/3 - 1, gx = 4*(xg*4 + xi) + tap%3 - 1;
    float val = 0.f;
    if ((unsigned)gy < HSIN && (unsigned)gx < HSIN)
      val = hsi[((n*CHS+ci)*HSIN + gy)*HSIN + gx];
    patch[kk][xi] = val;
  }
  __syncthreads();
  int co = tid;
  float bkv = bk[co];
  float a0 = bkv, a1 = bkv, a2 = bkv, a3 = bkv;
  #pragma unroll 8
  for (int kk = 0; kk < 1152; kk++){
    float4 p = *(const float4*)patch[kk];   // broadcast b128
    float w = wkt[kk*128 + co];             // coalesced, L2-hot
    a0 += p.x * w; a1 += p.y * w; a2 += p.z * w; a3 += p.w * w;
  }
  int base = ((n*CHS + co)*OS + y)*OS + xg*4;
  kw[base + 0] = lrelu(a0); kw[base + 1] = lrelu(a1);
  kw[base + 2] = lrelu(a2); kw[base + 3] = lrelu(a3);
}

// ---------------- attention scores: ar[n,i,c] = <q_i, k_c>/k0max ----------------
__global__ void att_kernel(const float* __restrict__ q, const float* __restrict__ kw,
                           const float* __restrict__ bn, float* __restrict__ ar){
  int n = blockIdx.x >> 7, c = blockIdx.x & 127;
  int tid = threadIdx.x;   // 128
  const float* kb = kw + (n*CHS + c)*1024;
  float kreg[8];
  #pragma unroll
  for (int u = 0; u < 8; u++) kreg[u] = kb[tid + u*128];
  float m = bn[n*8];
  #pragma unroll
  for (int i = 1; i < 8; i++) m = fmaxf(m, bn[n*8 + i]);
  __shared__ float red[2];
  for (int i = 0; i < 8; i++){
    const float* qb = q + (n*CMS + i)*1024;
    float s = 0.f;
    #pragma unroll
    for (int u = 0; u < 8; u++) s += qb[tid + u*128] * kreg[u];
    for (int off = 32; off; off >>= 1) s += __shfl_down(s, off);
    if ((tid & 63) == 0) red[tid >> 6] = s;
    __syncthreads();
    if (tid == 0) ar[(n*CMS + i)*CHS + c] = (red[0] + red[1]) / m;
    __syncthreads();
  }
}

// ---------------- softmax over c (scale 10), then /6 ----------------
__global__ void softmax_kernel(const float* __restrict__ ar, float* __restrict__ a2){
  int b = blockIdx.x;      // n*8+i, 16 blocks
  int tid = threadIdx.x;   // 128 = c
  float x = ar[b*128 + tid] * 10.f;
  __shared__ float red[2];
  float m = x;
  for (int off = 32; off; off >>= 1) m = fmaxf(m, __shfl_xor(m, off));
  if ((tid & 63) == 0) red[tid >> 6] = m;
  __syncthreads();
  m = fmaxf(red[0], red[1]);
  float e = expf(x - m);
  float s = e;
  for (int off = 32; off; off >>= 1) s += __shfl_xor(s, off);
  __syncthreads();
  if ((tid & 63) == 0) red[tid >> 6] = s;
  __syncthreads();
  s = red[0] + red[1];
  a2[b*128 + tid] = e / (6.f * s);
}

// ---------------- Weff: weT[n][i*9+tap][o] = sum_c Wr[o,c,tap]*a2[n,i,c] ----------------
__global__ void weff_kernel(const float* __restrict__ Wr, const float* __restrict__ a2,
                            float* __restrict__ weT){
  int o = blockIdx.x & 127, n = blockIdx.x >> 7;
  int t = threadIdx.x;     // 128, first 72 active
  if (t >= 72) return;
  int i = t / 9, tap = t % 9;
  const float* av = a2 + (n*CMS + i)*CHS;
  float s = 0.f;
  for (int c = 0; c < 128; c++)
    s += Wr[(o*128 + c)*9 + tap] * av[c];
  weT[(n*K72 + t)*CHS + o] = s;
}

// ---------------- final: res = lrelu(conv3x3_{Weff[n]}(v) + br), fp32 out ----------------
// Block = (xt,yt,n): 32x32 pixels x 128 o. 256 threads.
// Per wave-task: 16 wave-uniform o's (SGPR weights) x 64 pixels.
__global__ __launch_bounds__(256, 4)
void final_kernel(const float* __restrict__ v, const float* __restrict__ weT,
                  const float* __restrict__ br, float* __restrict__ out){
  __shared__ float vt[CMS][34][36];
  int xt = blockIdx.x, yt = blockIdx.y, n = blockIdx.z;
  int tid = threadIdx.x;
  for (int l = tid; l < CMS*34*34; l += 256){
    int i = l / 1156, r = l % 1156, yy = r / 34, xx = r % 34;
    int gy = yt*32 + yy - 1, gx = xt*32 + xx - 1;
    float val = 0.f;
    if ((unsigned)gy < HW && (unsigned)gx < HW)
      val = v[((n*CMS+i)*HW + gy)*HW + gx];
    vt[i][yy][xx] = val;
  }
  __syncthreads();
  int wid = __builtin_amdgcn_readfirstlane(tid >> 6);  // uniform wave id
  int lane = tid & 63;
  int lrow = lane >> 5, lx = lane & 31;
  const float* wt = weT + n*K72*CHS;
  // 128 tasks = 8 o-chunks x 16 pixel strips (2 rows x 32)
  for (int task = wid; task < 128; task += 4){
    int oc = task & 7;        // o = oc*16 + j  (uniform)
    int strip = task >> 3;
    int obase = oc * 16;
    int r0 = strip*2 + lrow;
    float acc[16];
    #pragma unroll
    for (int j = 0; j < 16; j++) acc[j] = 0.f;
    #pragma unroll
    for (int i = 0; i < 8; i++){
      #pragma unroll
      for (int tap = 0; tap < 9; tap++){
        float vv = vt[i][r0 + tap/3][lx + tap%3];
        const float* wrow = wt + (i*9 + tap)*CHS + obase;  // uniform -> s_load_dwordx16
        #pragma unroll
        for (int j = 0; j < 16; j++) acc[j] += wrow[j] * vv;
      }
    }
    int gy = yt*32 + r0, gx = xt*32 + lx;
    #pragma unroll
    for (int j = 0; j < 16; j++){
      int o = obase + j;
      out[((n*CHS + o)*HW + gy)*HW + gx] = lrelu(acc[j] + br[o]);
    }
  }
}

extern "C" void kernel_launch(void* const* d_in, const int* in_sizes, int n_in,
                              void* d_out, int out_size, void* d_ws, size_t ws_size,
                              hipStream_t stream){
  const float* hrms = (const float*)d_in[0];
  const float* msi  = (const float*)d_in[1];
  const float* hsi  = (const float*)d_in[2];
  const float* Wv   = (const float*)d_in[3];
  const float* bv   = (const float*)d_in[4];
  const float* Wq   = (const float*)d_in[5];
  const float* bq   = (const float*)d_in[6];
  const float* Wk   = (const float*)d_in[7];
  const float* bk   = (const float*)d_in[8];
  const float* Wr   = (const float*)d_in[9];
  const float* br   = (const float*)d_in[10];
  float* ws = (float*)d_ws;
  float* out = (float*)d_out;

  float* v   = ws + OFF_V;
  float* q   = ws + OFF_Q;
  float* kw  = ws + OFF_K;
  float* bn  = ws + OFF_BN;
  float* ar  = ws + OFF_AR;
  float* a2  = ws + OFF_A2;
  float* weT = ws + OFF_WE;
  float* wkt = ws + OFF_WKT;
  float* wvT = ws + OFF_WVT;

  hipLaunchKernelGGL(prep_kernel, dim3(579), dim3(256), 0, stream, Wk, Wv, wkt, wvT);
  hipLaunchKernelGGL(conv_v_kernel, dim3(16,16,2), dim3(256), 0, stream, hrms, wvT, bv, v);
  hipLaunchKernelGGL(conv_q_kernel, dim3(64), dim3(256), 0, stream, msi, Wq, bq, q);
  hipLaunchKernelGGL(bandnorm_kernel, dim3(16), dim3(256), 0, stream, q, bn);
  hipLaunchKernelGGL(conv_k_kernel, dim3(8,32,2), dim3(128), 0, stream, hsi, wkt, bk, kw);
  hipLaunchKernelGGL(att_kernel, dim3(256), dim3(128), 0, stream, q, kw, bn, ar);
  hipLaunchKernelGGL(softmax_kernel, dim3(16), dim3(128), 0, stream, ar, a2);
  hipLaunchKernelGGL(weff_kernel, dim3(256), dim3(128), 0, stream, Wr, a2, weT);
  hipLaunchKernelGGL(final_kernel, dim3(16,16,2), dim3(256), 0, stream, v, weT, br, out);
}